// Round 15
// baseline (1195.322 us; speedup 1.0000x reference)
//
#include <hip/hip_runtime.h>

typedef __attribute__((ext_vector_type(8))) short bf16x8;
typedef __attribute__((ext_vector_type(4))) float f32x4;
typedef __attribute__((ext_vector_type(4))) unsigned short u16x4;
typedef __attribute__((ext_vector_type(4))) unsigned u32x4;

#define CH 4096          // elements per sort chunk
#define MAXNT 8192       // max 16-row tiles in LDS hist (n <= 131072)

__device__ __forceinline__ unsigned short f2b(float f) {
    unsigned u = __builtin_bit_cast(unsigned, f);
    u += 0x7fffu + ((u >> 16) & 1u);   // round-to-nearest-even
    return (unsigned short)(u >> 16);
}

__global__ void zero_f32(float* __restrict__ p, long total) {
    long i = ((long)blockIdx.x * blockDim.x + threadIdx.x) * 4;
    if (i + 3 < total) {
        *(f32x4*)(p + i) = (f32x4){0.f, 0.f, 0.f, 0.f};
    } else {
        for (long t = i; t < total; ++t) p[t] = 0.f;
    }
}

__global__ void cvt_bf16(const float* __restrict__ x, unsigned short* __restrict__ o, long total) {
    long i = ((long)blockIdx.x * blockDim.x + threadIdx.x) * 4;
    if (i >= total) return;
    f32x4 v = *(const f32x4*)(x + i);
    u16x4 r;
#pragma unroll
    for (int t = 0; t < 4; ++t) r[t] = f2b(v[t]);
    *(u16x4*)(o + i) = r;
}

// Wb[k][frag f=kk*8+c][lane][j] = W[k][cin=kk*32+(lane>>4)*8+j][cout=c*16+(lane&15)]
__global__ void prep_w(const float* __restrict__ W1, const float* __restrict__ W2,
                       unsigned short* __restrict__ Wb1, unsigned short* __restrict__ Wb2,
                       int kelems) {
    int tid = blockIdx.x * 256 + threadIdx.x;
    if (tid >= 2 * kelems) return;
    int which = (tid >= kelems) ? 1 : 0;
    int rem = which ? (tid - kelems) : tid;
    int k = rem >> 14;
    int r2 = rem & 16383;
    int f = r2 >> 9;
    int lane = (r2 >> 3) & 63;
    int j = r2 & 7;
    int kk = f >> 3, c = f & 7;
    int cin = kk * 32 + (lane >> 4) * 8 + j;
    int cout = c * 16 + (lane & 15);
    const float* W = which ? W2 : W1;
    unsigned short* Wb = which ? Wb2 : Wb1;
    Wb[rem] = f2b(W[(size_t)k * 16384 + cin * 128 + cout]);
}

// ---------------- sort: bucket contributions by (k, 16-row tile); LDS atomics only ----------------

__global__ void pass_hist16(const int* __restrict__ io, int* __restrict__ cnt,
                            int n, int NT, int NCH) {
    __shared__ int hist[MAXNT];
    const int k = blockIdx.x / NCH, c = blockIdx.x % NCH;
    for (int i = threadIdx.x; i < NT; i += 256) hist[i] = 0;
    __syncthreads();
    const int m1 = min(n, (c + 1) * CH);
    const int* p = io + (size_t)k * n;
    for (int m = c * CH + threadIdx.x; m < m1; m += 256)
        atomicAdd(&hist[((unsigned)p[m]) >> 4], 1);
    __syncthreads();
    for (int rt = threadIdx.x; rt < NT; rt += 256)
        cnt[(size_t)(k * NT + rt) * NCH + c] = hist[rt];
}

__global__ void scan_part(const int* __restrict__ cnt, int* __restrict__ bsum, int nbins) {
    __shared__ int ls[256];
    int base = blockIdx.x * 4096 + threadIdx.x * 16;
    int s = 0;
#pragma unroll
    for (int i = 0; i < 16; ++i) { int idx = base + i; if (idx < nbins) s += cnt[idx]; }
    ls[threadIdx.x] = s; __syncthreads();
    for (int o = 128; o > 0; o >>= 1) {
        if ((int)threadIdx.x < o) ls[threadIdx.x] += ls[threadIdx.x + o];
        __syncthreads();
    }
    if (threadIdx.x == 0) bsum[blockIdx.x] = ls[0];
}

__global__ void scan_bsum(int* __restrict__ bsum, int nb, int* __restrict__ sptr, int nbins) {
    if (threadIdx.x == 0 && blockIdx.x == 0) {
        int run = 0;
        for (int i = 0; i < nb; ++i) { int t = bsum[i]; bsum[i] = run; run += t; }
        sptr[nbins] = run;
    }
}

__global__ void scan_final(const int* __restrict__ cnt, const int* __restrict__ bsum,
                           int* __restrict__ sptr, int nbins) {
    __shared__ int ls[256];
    const int tid = threadIdx.x;
    int base = blockIdx.x * 4096 + tid * 16;
    int loc[16];
    int s = 0;
#pragma unroll
    for (int i = 0; i < 16; ++i) {
        int idx = base + i;
        int v = (idx < nbins) ? cnt[idx] : 0;
        loc[i] = s; s += v;
    }
    ls[tid] = s; __syncthreads();
    for (int o = 1; o < 256; o <<= 1) {
        int add = (tid >= o) ? ls[tid - o] : 0;
        __syncthreads();
        ls[tid] += add;
        __syncthreads();
    }
    int excl = ls[tid] - s + bsum[blockIdx.x];
#pragma unroll
    for (int i = 0; i < 16; ++i) {
        int idx = base + i;
        if (idx < nbins) sptr[idx] = excl + loc[i];
    }
}

// pay[p] = (idx_in << 4) | (row & 15), grouped by (k, rt) via LDS-atomic ranks
__global__ void pass_scatter16(const int* __restrict__ io, const int* __restrict__ iin,
                               const int* __restrict__ sptr, unsigned* __restrict__ pay,
                               int n, int NT, int NCH) {
    __shared__ int base[MAXNT];
    const int k = blockIdx.x / NCH, c = blockIdx.x % NCH;
    for (int rt = threadIdx.x; rt < NT; rt += 256)
        base[rt] = sptr[(size_t)(k * NT + rt) * NCH + c];
    __syncthreads();
    const int m1 = min(n, (c + 1) * CH);
    const int* pio = io + (size_t)k * n;
    const int* pii = iin + (size_t)k * n;
    for (int m = c * CH + threadIdx.x; m < m1; m += 256) {
        int r = pio[m];
        int ii = pii[m];
        int p = atomicAdd(&base[r >> 4], 1);
        pay[p] = ((unsigned)ii << 4) | (unsigned)(r & 15);
    }
}

// ---------------- conv via MFMA-scatter v6: 16-row tiles (acc 32 regs) + K-split ----------
// Wave owns one 16-row output tile; blockIdx.y selects K-half and output buffer.
// Per pack of 16 contributions: gather-GEMM Y(16x128) = Xg @ W[k] then one-hot
// scatter MFMA acc(16x128) += S^T(16x16 used) @ Y. B K-slots 16..31 zeroed by lo-mask.
// No LDS, no barriers. Formulas are the R12-proven set minus the second o-plane.
__global__ __launch_bounds__(256) void conv_ms(
    const unsigned short* __restrict__ xin,   // [n,128] bf16
    const unsigned short* __restrict__ Wb,    // [K][32 frags][64][8] bf16
    const unsigned* __restrict__ pay,
    const int* __restrict__ sptr,
    float* __restrict__ h0, float* __restrict__ h1,
    int n, int NT, int NCH, int K, int KH)
{
    const int lane = threadIdx.x & 63;
    const int wv = threadIdx.x >> 6;
    const int kg = lane >> 4, l15 = lane & 15;
    const int rt = blockIdx.x * 4 + wv;
    if (rt >= NT) return;
    const int kh = blockIdx.y;
    const int k0 = kh * KH, k1 = min(K, k0 + KH);
    float* __restrict__ hout = kh ? h1 : h0;

    // exchange source lanes (loop-invariant), R11/R12-validated:
    const int sA = ((kg & 1) << 5) + l15;
    const int sB = sA + 16;
    const bool lo = (kg < 2);

    f32x4 acc[8];
#pragma unroll
    for (int c = 0; c < 8; ++c) acc[c] = (f32x4){0.f, 0.f, 0.f, 0.f};

    for (int k = k0; k < k1; ++k) {
        const unsigned short* wk = Wb + (size_t)k * 16384 + (size_t)lane * 8;
        const int e0 = sptr[(size_t)(k * NT + rt) * NCH];
        const int e1 = sptr[(size_t)(k * NT + rt + 1) * NCH];
        unsigned pv = (e0 + l15 < e1) ? pay[e0 + l15] : 0xFFFFFFFFu;

        for (int e = e0; e < e1; e += 16) {
            unsigned pvn = (e + 16 + l15 < e1) ? pay[e + 16 + l15] : 0xFFFFFFFFu;
            int ii = (pv != 0xFFFFFFFFu) ? (int)(pv >> 4) : 0;
            const unsigned short* xr = xin + (size_t)ii * 128 + kg * 8;

            // one-hot A frag (single o-plane): A2[m=l15][kd=kg*8+j] = (row(kd)==l15)
            bf16x8 oh;
#pragma unroll
            for (int j = 0; j < 8; ++j) {
                int q = kg * 8 + j;
                unsigned pq = (unsigned)__shfl((int)pv, q & 15, 64);
                int rl = (q < 16 && pq != 0xFFFFFFFFu) ? (int)(pq & 15u) : 99;
                oh[j] = (short)((rl == l15) ? 0x3F80 : 0);
            }

            // two c-halves to cap live registers
#pragma unroll
            for (int hh = 0; hh < 2; ++hh) {
                f32x4 y[4];
#pragma unroll
                for (int c4 = 0; c4 < 4; ++c4) y[c4] = (f32x4){0.f, 0.f, 0.f, 0.f};
#pragma unroll
                for (int kk = 0; kk < 4; ++kk) {
                    bf16x8 a = *(const bf16x8*)(xr + kk * 32);
#pragma unroll
                    for (int c4 = 0; c4 < 4; ++c4) {
                        bf16x8 b = *(const bf16x8*)(wk + (size_t)(kk * 8 + hh * 4 + c4) * 512);
                        y[c4] = __builtin_amdgcn_mfma_f32_16x16x32_bf16(a, b, y[c4], 0, 0, 0);
                    }
                }
                unsigned cv0[4], cv1[4];
#pragma unroll
                for (int c4 = 0; c4 < 4; ++c4) {
                    asm("v_cvt_pk_bf16_f32 %0, %1, %2" : "=v"(cv0[c4]) : "v"(y[c4][0]), "v"(y[c4][1]));
                    asm("v_cvt_pk_bf16_f32 %0, %1, %2" : "=v"(cv1[c4]) : "v"(y[c4][2]), "v"(y[c4][3]));
                }
#pragma unroll
                for (int c4 = 0; c4 < 4; ++c4) {
                    unsigned v0 = (unsigned)__shfl((int)cv0[c4], sA, 64);
                    unsigned v1 = (unsigned)__shfl((int)cv1[c4], sA, 64);
                    unsigned v2 = (unsigned)__shfl((int)cv0[c4], sB, 64);
                    unsigned v3 = (unsigned)__shfl((int)cv1[c4], sB, 64);
                    u32x4 t = (u32x4){lo ? v0 : 0u, lo ? v1 : 0u, lo ? v2 : 0u, lo ? v3 : 0u};
                    bf16x8 bb = __builtin_bit_cast(bf16x8, t);
                    int ci = hh * 4 + c4;
                    acc[ci] = __builtin_amdgcn_mfma_f32_16x16x32_bf16(oh, bb, acc[ci], 0, 0, 0);
                }
            }
            pv = pvn;
        }
    }

    // epilogue: write partial h rows (16-row tile, full overwrite of this buffer)
    const int r0 = rt * 16;
#pragma unroll
    for (int c = 0; c < 8; ++c)
#pragma unroll
        for (int j = 0; j < 4; ++j) {
            int r = r0 + kg * 4 + j;
            if (r < n) hout[(size_t)r * 128 + l15 + 16 * c] = acc[c][j];
        }
}

// ---------------- fallback: atomic conv (R1, proven) ----------------
__global__ __launch_bounds__(512) void conv_atomic(
    const unsigned short* __restrict__ xin, const unsigned short* __restrict__ Wb,
    const int* __restrict__ idx_in, const int* __restrict__ idx_out,
    float* __restrict__ out, int n) {
    __shared__ unsigned short wlds[16384];
    const int k = blockIdx.y;
    const int m0 = blockIdx.x * 256;
    {
        const bf16x8* src = (const bf16x8*)(Wb + (size_t)k * 16384);
        bf16x8* dst = (bf16x8*)wlds;
        for (int i = threadIdx.x; i < 2048; i += 512) dst[i] = src[i];
    }
    __syncthreads();
    const int wave = threadIdx.x >> 6;
    const int lane = threadIdx.x & 63;
    const int kg = lane >> 4;
    const int l15 = lane & 15;
    const int* iin  = idx_in  + (size_t)k * n;
    const int* iout = idx_out + (size_t)k * n;
    const int mbase = m0 + wave * 32;
    int arow0, arow1;
    { int m = mbase + l15;      arow0 = (m < n) ? iin[m] : 0; }
    { int m = mbase + 16 + l15; arow1 = (m < n) ? iin[m] : 0; }
    f32x4 acc[2][8];
#pragma unroll
    for (int s = 0; s < 2; ++s)
#pragma unroll
        for (int c = 0; c < 8; ++c) acc[s][c] = (f32x4){0.f, 0.f, 0.f, 0.f};
#pragma unroll
    for (int kk = 0; kk < 4; ++kk) {
        bf16x8 a0 = *(const bf16x8*)(xin + (size_t)arow0 * 128 + kk * 32 + kg * 8);
        bf16x8 a1 = *(const bf16x8*)(xin + (size_t)arow1 * 128 + kk * 32 + kg * 8);
#pragma unroll
        for (int c = 0; c < 8; ++c) {
            bf16x8 b = *(const bf16x8*)(wlds + ((kk * 8 + c) * 64 + lane) * 8);
            acc[0][c] = __builtin_amdgcn_mfma_f32_16x16x32_bf16(a0, b, acc[0][c], 0, 0, 0);
            acc[1][c] = __builtin_amdgcn_mfma_f32_16x16x32_bf16(a1, b, acc[1][c], 0, 0, 0);
        }
    }
#pragma unroll
    for (int s = 0; s < 2; ++s)
#pragma unroll
        for (int j = 0; j < 4; ++j) {
            int m = mbase + s * 16 + kg * 4 + j;
            if (m < n) {
                long orow = iout[m];
                float* dst = out + orow * 128 + l15;
#pragma unroll
                for (int c = 0; c < 8; ++c) atomicAdd(dst + c * 16, acc[s][c][j]);
            }
        }
}

// ---------------- BN epilogues (true layout f32 h; all proven) ----------------

__global__ void bn_stats(const float* __restrict__ h, float* __restrict__ stats, int n) {
    const int c = threadIdx.x & 127;
    const int half = threadIdx.x >> 7;
    const int r0 = blockIdx.x * 256;
    const int rend = min(r0 + 256, n);
    float s = 0.f, s2 = 0.f;
    for (int r = r0 + half; r < rend; r += 2) {
        float v = h[(size_t)r * 128 + c];
        s += v; s2 += v * v;
    }
    __shared__ float ls[256], ls2[256];
    ls[threadIdx.x] = s; ls2[threadIdx.x] = s2;
    __syncthreads();
    if (half == 0) {
        atomicAdd(&stats[c], ls[c] + ls[128 + c]);
        atomicAdd(&stats[128 + c], ls2[c] + ls2[128 + c]);
    }
}

// merge K-split halves (h0 += h1) with fused BN stats
__global__ void bn_stats_merge(float* __restrict__ h0, const float* __restrict__ h1,
                               float* __restrict__ stats, int n) {
    const int c = threadIdx.x & 127;
    const int half = threadIdx.x >> 7;
    const int r0 = blockIdx.x * 256;
    const int rend = min(r0 + 256, n);
    float s = 0.f, s2 = 0.f;
    for (int r = r0 + half; r < rend; r += 2) {
        size_t idx = (size_t)r * 128 + c;
        float v = h0[idx] + h1[idx];
        h0[idx] = v;
        s += v; s2 += v * v;
    }
    __shared__ float ls[256], ls2[256];
    ls[threadIdx.x] = s; ls2[threadIdx.x] = s2;
    __syncthreads();
    if (half == 0) {
        atomicAdd(&stats[c], ls[c] + ls[128 + c]);
        atomicAdd(&stats[128 + c], ls2[c] + ls2[128 + c]);
    }
}

__global__ void bn_finalize(float* stats, const float* __restrict__ g,
                            const float* __restrict__ b, float inv_n) {
    int c = threadIdx.x;
    float mu = stats[c] * inv_n;
    float var = fmaxf(stats[128 + c] * inv_n - mu * mu, 0.f);
    float sc = g[c] * rsqrtf(var + 1e-5f);
    stats[256 + c] = sc;
    stats[384 + c] = b[c] - mu * sc;
}

__global__ void bn_relu_bf16(const float* __restrict__ h, const float* __restrict__ stats,
                             unsigned short* __restrict__ hb, long total) {
    long i = ((long)blockIdx.x * 256 + threadIdx.x) * 4;
    if (i >= total) return;
    int c = (int)(i & 127);
    f32x4 v = *(const f32x4*)(h + i);
    u16x4 r;
#pragma unroll
    for (int t = 0; t < 4; ++t) {
        float y = fmaxf(v[t] * stats[256 + c + t] + stats[384 + c + t], 0.f);
        r[t] = f2b(y);
    }
    *(u16x4*)(hb + i) = r;
}

__global__ void bn_res_relu(float* __restrict__ out, const float* __restrict__ stats,
                            const float* __restrict__ x, long total) {
    long i = ((long)blockIdx.x * 256 + threadIdx.x) * 4;
    if (i >= total) return;
    int c = (int)(i & 127);
    f32x4 h = *(const f32x4*)(out + i);
    f32x4 xv = *(const f32x4*)(x + i);
    f32x4 r;
#pragma unroll
    for (int t = 0; t < 4; ++t)
        r[t] = fmaxf(h[t] * stats[256 + c + t] + stats[384 + c + t] + xv[t], 0.f);
    *(f32x4*)(out + i) = r;
}

extern "C" void kernel_launch(void* const* d_in, const int* in_sizes, int n_in,
                              void* d_out, int out_size, void* d_ws, size_t ws_size,
                              hipStream_t stream) {
    const float* x  = (const float*)d_in[0];
    const float* W1 = (const float*)d_in[1];
    const float* g1 = (const float*)d_in[2];
    const float* b1 = (const float*)d_in[3];
    const float* W2 = (const float*)d_in[4];
    const float* g2 = (const float*)d_in[5];
    const float* b2 = (const float*)d_in[6];
    const int* idx_in  = (const int*)d_in[7];
    const int* idx_out = (const int*)d_in[8];

    const int n = in_sizes[0] / 128;
    const int K = in_sizes[1] / 16384;
    const long total = (long)n * 128;
    const int nk = K * n;
    float* acc = (float*)d_out;               // h (merged) lives in d_out

    char* ws = (char*)d_ws;
    auto align256 = [](size_t v) { return (v + 255) & ~255ULL; };

    const int NT  = (n + 15) / 16;
    const int NCH = (n + CH - 1) / CH;
    const long nbinsS = (long)K * NT * NCH;
    const long nbS = (nbinsS + 4095) / 4096;

    size_t off = 0;
    const size_t o_slabA = off; off = align256(off + (size_t)total * 2);
    const size_t o_Wb1   = off; off = align256(off + (size_t)K * 16384 * 2);
    const size_t o_Wb2   = off; off = align256(off + (size_t)K * 16384 * 2);
    const size_t o_stats = off; off = align256(off + 1024 * 4);
    const size_t o_h2    = off; off = align256(off + (size_t)total * 4);
    const size_t o_pay   = off; off = align256(off + (size_t)nk * 4);
    const size_t o_cnt   = off; off = align256(off + (size_t)nbinsS * 4);
    const size_t o_sptr  = off; off = align256(off + ((size_t)nbinsS + 1) * 4);
    const size_t o_bsum  = off; off = align256(off + ((size_t)nbS + 2) * 4);
    const bool fast_ok = (NT <= MAXNT) && (off <= ws_size);

    unsigned short* slabA = (unsigned short*)(ws + o_slabA);
    unsigned short* Wb1   = (unsigned short*)(ws + o_Wb1);
    unsigned short* Wb2   = (unsigned short*)(ws + o_Wb2);
    float* stats          = (float*)(ws + o_stats);
    float* h2             = (float*)(ws + o_h2);
    unsigned* pay         = (unsigned*)(ws + o_pay);
    int* cnt              = (int*)(ws + o_cnt);
    int* sptr             = (int*)(ws + o_sptr);
    int* bsum             = (int*)(ws + o_bsum);

    const dim3 b256(256);
    const int gCvt = (int)((total / 4 + 255) / 256);
    const int kelems = K * 16384;

    hipLaunchKernelGGL(zero_f32, dim3(1), b256, 0, stream, stats, (long)1024);
    hipLaunchKernelGGL(cvt_bf16, dim3(gCvt), b256, 0, stream, x, slabA, total);
    hipLaunchKernelGGL(prep_w, dim3((2 * kelems + 255) / 256), b256, 0, stream,
                       W1, W2, Wb1, Wb2, kelems);

    if (fast_ok) {
        const int gSort = K * NCH;
        hipLaunchKernelGGL(pass_hist16, dim3(gSort), b256, 0, stream, idx_out, cnt, n, NT, NCH);
        hipLaunchKernelGGL(scan_part, dim3((int)nbS), b256, 0, stream, cnt, bsum, (int)nbinsS);
        hipLaunchKernelGGL(scan_bsum, dim3(1), dim3(64), 0, stream, bsum, (int)nbS, sptr, (int)nbinsS);
        hipLaunchKernelGGL(scan_final, dim3((int)nbS), b256, 0, stream, cnt, bsum, sptr, (int)nbinsS);
        hipLaunchKernelGGL(pass_scatter16, dim3(gSort), b256, 0, stream,
                           idx_out, idx_in, sptr, pay, n, NT, NCH);

        const int gConv = (NT + 3) / 4;
        const int KH = (K + 1) / 2;
        for (int conv = 0; conv < 2; ++conv) {
            const unsigned short* Wb = conv ? Wb2 : Wb1;
            float* st = stats + conv * 512;
            hipLaunchKernelGGL(conv_ms, dim3(gConv, 2), b256, 0, stream,
                               slabA, Wb, pay, sptr, acc, h2, n, NT, NCH, K, KH);
            hipLaunchKernelGGL(bn_stats_merge, dim3((n + 255) / 256), b256, 0, stream,
                               acc, h2, st, n);
            hipLaunchKernelGGL(bn_finalize, dim3(1), dim3(128), 0, stream, st,
                               conv ? g2 : g1, conv ? b2 : b1, 1.0f / n);
            if (conv == 0)
                hipLaunchKernelGGL(bn_relu_bf16, dim3(gCvt), b256, 0, stream, acc, st, slabA, total);
            else
                hipLaunchKernelGGL(bn_res_relu, dim3(gCvt), b256, 0, stream, acc, st, x, total);
        }
    } else {
        for (int conv = 0; conv < 2; ++conv) {
            const unsigned short* Wb = conv ? Wb2 : Wb1;
            float* st = stats + conv * 512;
            hipLaunchKernelGGL(zero_f32, dim3(gCvt), b256, 0, stream, acc, total);
            hipLaunchKernelGGL(conv_atomic, dim3((n + 255) / 256, K), dim3(512), 0, stream,
                               slabA, Wb, idx_in, idx_out, acc, n);
            hipLaunchKernelGGL(bn_stats, dim3((n + 255) / 256), b256, 0, stream, acc, st, n);
            hipLaunchKernelGGL(bn_finalize, dim3(1), dim3(128), 0, stream, st,
                               conv ? g2 : g1, conv ? b2 : b1, 1.0f / n);
            if (conv == 0)
                hipLaunchKernelGGL(bn_relu_bf16, dim3(gCvt), b256, 0, stream, acc, st, slabA, total);
            else
                hipLaunchKernelGGL(bn_res_relu, dim3(gCvt), b256, 0, stream, acc, st, x, total);
        }
    }
}

// Round 16
// 945.575 us; speedup vs baseline: 1.2641x; 1.2641x over previous
//
#include <hip/hip_runtime.h>

typedef __attribute__((ext_vector_type(8))) short bf16x8;
typedef __attribute__((ext_vector_type(4))) float f32x4;
typedef __attribute__((ext_vector_type(4))) unsigned short u16x4;
typedef __attribute__((ext_vector_type(4))) unsigned u32x4;

#define CH 4096          // elements per sort chunk
#define MAXNT 4096       // max 32-row tiles in LDS hist (n <= 131072)

__device__ __forceinline__ unsigned short f2b(float f) {
    unsigned u = __builtin_bit_cast(unsigned, f);
    u += 0x7fffu + ((u >> 16) & 1u);   // round-to-nearest-even
    return (unsigned short)(u >> 16);
}

__global__ void zero_f32(float* __restrict__ p, long total) {
    long i = ((long)blockIdx.x * blockDim.x + threadIdx.x) * 4;
    if (i + 3 < total) {
        *(f32x4*)(p + i) = (f32x4){0.f, 0.f, 0.f, 0.f};
    } else {
        for (long t = i; t < total; ++t) p[t] = 0.f;
    }
}

__global__ void cvt_bf16(const float* __restrict__ x, unsigned short* __restrict__ o, long total) {
    long i = ((long)blockIdx.x * blockDim.x + threadIdx.x) * 4;
    if (i >= total) return;
    f32x4 v = *(const f32x4*)(x + i);
    u16x4 r;
#pragma unroll
    for (int t = 0; t < 4; ++t) r[t] = f2b(v[t]);
    *(u16x4*)(o + i) = r;
}

// Wb[k][frag f=kk*8+c][lane][j] = W[k][cin=kk*32+(lane>>4)*8+j][cout=c*16+(lane&15)]
__global__ void prep_w(const float* __restrict__ W1, const float* __restrict__ W2,
                       unsigned short* __restrict__ Wb1, unsigned short* __restrict__ Wb2,
                       int kelems) {
    int tid = blockIdx.x * 256 + threadIdx.x;
    if (tid >= 2 * kelems) return;
    int which = (tid >= kelems) ? 1 : 0;
    int rem = which ? (tid - kelems) : tid;
    int k = rem >> 14;
    int r2 = rem & 16383;
    int f = r2 >> 9;
    int lane = (r2 >> 3) & 63;
    int j = r2 & 7;
    int kk = f >> 3, c = f & 7;
    int cin = kk * 32 + (lane >> 4) * 8 + j;
    int cout = c * 16 + (lane & 15);
    const float* W = which ? W2 : W1;
    unsigned short* Wb = which ? Wb2 : Wb1;
    Wb[rem] = f2b(W[(size_t)k * 16384 + cin * 128 + cout]);
}

// ---------------- sort: bucket contributions by (k, 32-row tile); LDS atomics only ----------------

__global__ void pass_hist32(const int* __restrict__ io, int* __restrict__ cnt,
                            int n, int NT, int NCH) {
    __shared__ int hist[MAXNT];
    const int k = blockIdx.x / NCH, c = blockIdx.x % NCH;
    for (int i = threadIdx.x; i < NT; i += 256) hist[i] = 0;
    __syncthreads();
    const int m1 = min(n, (c + 1) * CH);
    const int* p = io + (size_t)k * n;
    for (int m = c * CH + threadIdx.x; m < m1; m += 256)
        atomicAdd(&hist[((unsigned)p[m]) >> 5], 1);
    __syncthreads();
    for (int rt = threadIdx.x; rt < NT; rt += 256)
        cnt[(size_t)(k * NT + rt) * NCH + c] = hist[rt];
}

__global__ void scan_part(const int* __restrict__ cnt, int* __restrict__ bsum, int nbins) {
    __shared__ int ls[256];
    int base = blockIdx.x * 4096 + threadIdx.x * 16;
    int s = 0;
#pragma unroll
    for (int i = 0; i < 16; ++i) { int idx = base + i; if (idx < nbins) s += cnt[idx]; }
    ls[threadIdx.x] = s; __syncthreads();
    for (int o = 128; o > 0; o >>= 1) {
        if ((int)threadIdx.x < o) ls[threadIdx.x] += ls[threadIdx.x + o];
        __syncthreads();
    }
    if (threadIdx.x == 0) bsum[blockIdx.x] = ls[0];
}

__global__ void scan_bsum(int* __restrict__ bsum, int nb, int* __restrict__ sptr, int nbins) {
    if (threadIdx.x == 0 && blockIdx.x == 0) {
        int run = 0;
        for (int i = 0; i < nb; ++i) { int t = bsum[i]; bsum[i] = run; run += t; }
        sptr[nbins] = run;
    }
}

__global__ void scan_final(const int* __restrict__ cnt, const int* __restrict__ bsum,
                           int* __restrict__ sptr, int nbins) {
    __shared__ int ls[256];
    const int tid = threadIdx.x;
    int base = blockIdx.x * 4096 + tid * 16;
    int loc[16];
    int s = 0;
#pragma unroll
    for (int i = 0; i < 16; ++i) {
        int idx = base + i;
        int v = (idx < nbins) ? cnt[idx] : 0;
        loc[i] = s; s += v;
    }
    ls[tid] = s; __syncthreads();
    for (int o = 1; o < 256; o <<= 1) {
        int add = (tid >= o) ? ls[tid - o] : 0;
        __syncthreads();
        ls[tid] += add;
        __syncthreads();
    }
    int excl = ls[tid] - s + bsum[blockIdx.x];
#pragma unroll
    for (int i = 0; i < 16; ++i) {
        int idx = base + i;
        if (idx < nbins) sptr[idx] = excl + loc[i];
    }
}

// pay[p] = (idx_in << 5) | (row & 31), grouped by (k, rt) via LDS-atomic ranks
__global__ void pass_scatter32(const int* __restrict__ io, const int* __restrict__ iin,
                               const int* __restrict__ sptr, unsigned* __restrict__ pay,
                               int n, int NT, int NCH) {
    __shared__ int base[MAXNT];
    const int k = blockIdx.x / NCH, c = blockIdx.x % NCH;
    for (int rt = threadIdx.x; rt < NT; rt += 256)
        base[rt] = sptr[(size_t)(k * NT + rt) * NCH + c];
    __syncthreads();
    const int m1 = min(n, (c + 1) * CH);
    const int* pio = io + (size_t)k * n;
    const int* pii = iin + (size_t)k * n;
    for (int m = c * CH + threadIdx.x; m < m1; m += 256) {
        int r = pio[m];
        int ii = pii[m];
        int p = atomicAdd(&base[r >> 5], 1);
        pay[p] = ((unsigned)ii << 5) | (unsigned)(r & 31);
    }
}

// ---------------- conv via MFMA-scatter v7: R14 body + block-shared LDS W (k-lockstep) ----------
// Wave owns one 32-row output tile; blockIdx.y selects K-half and output buffer.
// Per k: stage W[k] (32 KB) to LDS once per block (2 barriers), then each wave
// processes its (k,rt) segment in 16-contribution packs reading b-frags from LDS.
__global__ __launch_bounds__(256) void conv_ms(
    const unsigned short* __restrict__ xin,   // [n,128] bf16
    const unsigned short* __restrict__ Wb,    // [K][32 frags][64][8] bf16
    const unsigned* __restrict__ pay,
    const int* __restrict__ sptr,
    float* __restrict__ h0, float* __restrict__ h1,
    int n, int NT, int NCH, int K, int KH)
{
    __shared__ unsigned short wl[16384];      // W[k] frags, 32 KB
    const int lane = threadIdx.x & 63;
    const int wv = threadIdx.x >> 6;
    const int kg = lane >> 4, l15 = lane & 15;
    const int rt = blockIdx.x * 4 + wv;       // NO early return: barriers below
    const int kh = blockIdx.y;
    const int k0 = kh * KH, k1 = min(K, k0 + KH);
    float* __restrict__ hout = kh ? h1 : h0;

    // exchange source lanes (loop-invariant), R11/R12-validated:
    const int sA = ((kg & 1) << 5) + l15;
    const int sB = sA + 16;
    const bool lo = (kg < 2);

    f32x4 acc[2][8];
#pragma unroll
    for (int o = 0; o < 2; ++o)
#pragma unroll
        for (int c = 0; c < 8; ++c) acc[o][c] = (f32x4){0.f, 0.f, 0.f, 0.f};

    for (int k = k0; k < k1; ++k) {
        __syncthreads();                      // all waves done reading wl[k-1]
        {
            const bf16x8* src = (const bf16x8*)(Wb + (size_t)k * 16384);
            bf16x8* dst = (bf16x8*)wl;
#pragma unroll
            for (int i = 0; i < 8; ++i) dst[i * 256 + threadIdx.x] = src[i * 256 + threadIdx.x];
        }
        __syncthreads();                      // wl[k] ready

        if (rt < NT) {
            const unsigned short* wk = wl + (size_t)lane * 8;
            const int e0 = sptr[(size_t)(k * NT + rt) * NCH];
            const int e1 = sptr[(size_t)(k * NT + rt + 1) * NCH];
            unsigned pv = (e0 + l15 < e1) ? pay[e0 + l15] : 0xFFFFFFFFu;

            for (int e = e0; e < e1; e += 16) {
                unsigned pvn = (e + 16 + l15 < e1) ? pay[e + 16 + l15] : 0xFFFFFFFFu;
                int ii = (pv != 0xFFFFFFFFu) ? (int)(pv >> 5) : 0;
                const unsigned short* xr = xin + (size_t)ii * 128 + kg * 8;

                // one-hot A frags (R11-validated)
                bf16x8 oh0, oh1;
#pragma unroll
                for (int j = 0; j < 8; ++j) {
                    int q = kg * 8 + j;
                    unsigned pq = (unsigned)__shfl((int)pv, q & 15, 64);
                    int rl = (q < 16 && pq != 0xFFFFFFFFu) ? (int)(pq & 31u) : 999;
                    oh0[j] = (short)((rl == l15) ? 0x3F80 : 0);
                    oh1[j] = (short)((rl == 16 + l15) ? 0x3F80 : 0);
                }

                // two c-halves to cap live registers
#pragma unroll
                for (int hh = 0; hh < 2; ++hh) {
                    f32x4 y[4];
#pragma unroll
                    for (int c4 = 0; c4 < 4; ++c4) y[c4] = (f32x4){0.f, 0.f, 0.f, 0.f};
#pragma unroll
                    for (int kk = 0; kk < 4; ++kk) {
                        bf16x8 a = *(const bf16x8*)(xr + kk * 32);
#pragma unroll
                        for (int c4 = 0; c4 < 4; ++c4) {
                            bf16x8 b = *(const bf16x8*)(wk + (size_t)(kk * 8 + hh * 4 + c4) * 512);
                            y[c4] = __builtin_amdgcn_mfma_f32_16x16x32_bf16(a, b, y[c4], 0, 0, 0);
                        }
                    }
                    unsigned cv0[4], cv1[4];
#pragma unroll
                    for (int c4 = 0; c4 < 4; ++c4) {
                        asm("v_cvt_pk_bf16_f32 %0, %1, %2" : "=v"(cv0[c4]) : "v"(y[c4][0]), "v"(y[c4][1]));
                        asm("v_cvt_pk_bf16_f32 %0, %1, %2" : "=v"(cv1[c4]) : "v"(y[c4][2]), "v"(y[c4][3]));
                    }
#pragma unroll
                    for (int c4 = 0; c4 < 4; ++c4) {
                        unsigned v0 = (unsigned)__shfl((int)cv0[c4], sA, 64);
                        unsigned v1 = (unsigned)__shfl((int)cv1[c4], sA, 64);
                        unsigned v2 = (unsigned)__shfl((int)cv0[c4], sB, 64);
                        unsigned v3 = (unsigned)__shfl((int)cv1[c4], sB, 64);
                        u32x4 t = (u32x4){lo ? v0 : 0u, lo ? v1 : 0u, lo ? v2 : 0u, lo ? v3 : 0u};
                        bf16x8 bb = __builtin_bit_cast(bf16x8, t);
                        int ci = hh * 4 + c4;
                        acc[0][ci] = __builtin_amdgcn_mfma_f32_16x16x32_bf16(oh0, bb, acc[0][ci], 0, 0, 0);
                        acc[1][ci] = __builtin_amdgcn_mfma_f32_16x16x32_bf16(oh1, bb, acc[1][ci], 0, 0, 0);
                    }
                }
                pv = pvn;
            }
        }
    }

    // epilogue: write partial h rows (full overwrite of this buffer)
    if (rt < NT) {
        const int r0 = rt * 32;
#pragma unroll
        for (int o = 0; o < 2; ++o)
#pragma unroll
            for (int c = 0; c < 8; ++c)
#pragma unroll
                for (int j = 0; j < 4; ++j) {
                    int r = r0 + o * 16 + kg * 4 + j;
                    if (r < n) hout[(size_t)r * 128 + l15 + 16 * c] = acc[o][c][j];
                }
    }
}

// ---------------- fallback: atomic conv (R1, proven) ----------------
__global__ __launch_bounds__(512) void conv_atomic(
    const unsigned short* __restrict__ xin, const unsigned short* __restrict__ Wb,
    const int* __restrict__ idx_in, const int* __restrict__ idx_out,
    float* __restrict__ out, int n) {
    __shared__ unsigned short wlds[16384];
    const int k = blockIdx.y;
    const int m0 = blockIdx.x * 256;
    {
        const bf16x8* src = (const bf16x8*)(Wb + (size_t)k * 16384);
        bf16x8* dst = (bf16x8*)wlds;
        for (int i = threadIdx.x; i < 2048; i += 512) dst[i] = src[i];
    }
    __syncthreads();
    const int wave = threadIdx.x >> 6;
    const int lane = threadIdx.x & 63;
    const int kg = lane >> 4;
    const int l15 = lane & 15;
    const int* iin  = idx_in  + (size_t)k * n;
    const int* iout = idx_out + (size_t)k * n;
    const int mbase = m0 + wave * 32;
    int arow0, arow1;
    { int m = mbase + l15;      arow0 = (m < n) ? iin[m] : 0; }
    { int m = mbase + 16 + l15; arow1 = (m < n) ? iin[m] : 0; }
    f32x4 acc[2][8];
#pragma unroll
    for (int s = 0; s < 2; ++s)
#pragma unroll
        for (int c = 0; c < 8; ++c) acc[s][c] = (f32x4){0.f, 0.f, 0.f, 0.f};
#pragma unroll
    for (int kk = 0; kk < 4; ++kk) {
        bf16x8 a0 = *(const bf16x8*)(xin + (size_t)arow0 * 128 + kk * 32 + kg * 8);
        bf16x8 a1 = *(const bf16x8*)(xin + (size_t)arow1 * 128 + kk * 32 + kg * 8);
#pragma unroll
        for (int c = 0; c < 8; ++c) {
            bf16x8 b = *(const bf16x8*)(wlds + ((kk * 8 + c) * 64 + lane) * 8);
            acc[0][c] = __builtin_amdgcn_mfma_f32_16x16x32_bf16(a0, b, acc[0][c], 0, 0, 0);
            acc[1][c] = __builtin_amdgcn_mfma_f32_16x16x32_bf16(a1, b, acc[1][c], 0, 0, 0);
        }
    }
#pragma unroll
    for (int s = 0; s < 2; ++s)
#pragma unroll
        for (int j = 0; j < 4; ++j) {
            int m = mbase + s * 16 + kg * 4 + j;
            if (m < n) {
                long orow = iout[m];
                float* dst = out + orow * 128 + l15;
#pragma unroll
                for (int c = 0; c < 8; ++c) atomicAdd(dst + c * 16, acc[s][c][j]);
            }
        }
}

// ---------------- BN epilogues (true layout f32 h; all proven) ----------------

__global__ void bn_stats(const float* __restrict__ h, float* __restrict__ stats, int n) {
    const int c = threadIdx.x & 127;
    const int half = threadIdx.x >> 7;
    const int r0 = blockIdx.x * 256;
    const int rend = min(r0 + 256, n);
    float s = 0.f, s2 = 0.f;
    for (int r = r0 + half; r < rend; r += 2) {
        float v = h[(size_t)r * 128 + c];
        s += v; s2 += v * v;
    }
    __shared__ float ls[256], ls2[256];
    ls[threadIdx.x] = s; ls2[threadIdx.x] = s2;
    __syncthreads();
    if (half == 0) {
        atomicAdd(&stats[c], ls[c] + ls[128 + c]);
        atomicAdd(&stats[128 + c], ls2[c] + ls2[128 + c]);
    }
}

// merge K-split halves (h0 += h1) with fused BN stats
__global__ void bn_stats_merge(float* __restrict__ h0, const float* __restrict__ h1,
                               float* __restrict__ stats, int n) {
    const int c = threadIdx.x & 127;
    const int half = threadIdx.x >> 7;
    const int r0 = blockIdx.x * 256;
    const int rend = min(r0 + 256, n);
    float s = 0.f, s2 = 0.f;
    for (int r = r0 + half; r < rend; r += 2) {
        size_t idx = (size_t)r * 128 + c;
        float v = h0[idx] + h1[idx];
        h0[idx] = v;
        s += v; s2 += v * v;
    }
    __shared__ float ls[256], ls2[256];
    ls[threadIdx.x] = s; ls2[threadIdx.x] = s2;
    __syncthreads();
    if (half == 0) {
        atomicAdd(&stats[c], ls[c] + ls[128 + c]);
        atomicAdd(&stats[128 + c], ls2[c] + ls2[128 + c]);
    }
}

__global__ void bn_finalize(float* stats, const float* __restrict__ g,
                            const float* __restrict__ b, float inv_n) {
    int c = threadIdx.x;
    float mu = stats[c] * inv_n;
    float var = fmaxf(stats[128 + c] * inv_n - mu * mu, 0.f);
    float sc = g[c] * rsqrtf(var + 1e-5f);
    stats[256 + c] = sc;
    stats[384 + c] = b[c] - mu * sc;
}

__global__ void bn_relu_bf16(const float* __restrict__ h, const float* __restrict__ stats,
                             unsigned short* __restrict__ hb, long total) {
    long i = ((long)blockIdx.x * 256 + threadIdx.x) * 4;
    if (i >= total) return;
    int c = (int)(i & 127);
    f32x4 v = *(const f32x4*)(h + i);
    u16x4 r;
#pragma unroll
    for (int t = 0; t < 4; ++t) {
        float y = fmaxf(v[t] * stats[256 + c + t] + stats[384 + c + t], 0.f);
        r[t] = f2b(y);
    }
    *(u16x4*)(hb + i) = r;
}

__global__ void bn_res_relu(float* __restrict__ out, const float* __restrict__ stats,
                            const float* __restrict__ x, long total) {
    long i = ((long)blockIdx.x * 256 + threadIdx.x) * 4;
    if (i >= total) return;
    int c = (int)(i & 127);
    f32x4 h = *(const f32x4*)(out + i);
    f32x4 xv = *(const f32x4*)(x + i);
    f32x4 r;
#pragma unroll
    for (int t = 0; t < 4; ++t)
        r[t] = fmaxf(h[t] * stats[256 + c + t] + stats[384 + c + t] + xv[t], 0.f);
    *(f32x4*)(out + i) = r;
}

extern "C" void kernel_launch(void* const* d_in, const int* in_sizes, int n_in,
                              void* d_out, int out_size, void* d_ws, size_t ws_size,
                              hipStream_t stream) {
    const float* x  = (const float*)d_in[0];
    const float* W1 = (const float*)d_in[1];
    const float* g1 = (const float*)d_in[2];
    const float* b1 = (const float*)d_in[3];
    const float* W2 = (const float*)d_in[4];
    const float* g2 = (const float*)d_in[5];
    const float* b2 = (const float*)d_in[6];
    const int* idx_in  = (const int*)d_in[7];
    const int* idx_out = (const int*)d_in[8];

    const int n = in_sizes[0] / 128;
    const int K = in_sizes[1] / 16384;
    const long total = (long)n * 128;
    const int nk = K * n;
    float* acc = (float*)d_out;               // h (merged) lives in d_out

    char* ws = (char*)d_ws;
    auto align256 = [](size_t v) { return (v + 255) & ~255ULL; };

    const int NT  = (n + 31) / 32;
    const int NCH = (n + CH - 1) / CH;
    const long nbinsS = (long)K * NT * NCH;
    const long nbS = (nbinsS + 4095) / 4096;

    size_t off = 0;
    const size_t o_slabA = off; off = align256(off + (size_t)total * 2);
    const size_t o_Wb1   = off; off = align256(off + (size_t)K * 16384 * 2);
    const size_t o_Wb2   = off; off = align256(off + (size_t)K * 16384 * 2);
    const size_t o_stats = off; off = align256(off + 1024 * 4);
    const size_t o_h2    = off; off = align256(off + (size_t)total * 4);
    const size_t o_pay   = off; off = align256(off + (size_t)nk * 4);
    const size_t o_cnt   = off; off = align256(off + (size_t)nbinsS * 4);
    const size_t o_sptr  = off; off = align256(off + ((size_t)nbinsS + 1) * 4);
    const size_t o_bsum  = off; off = align256(off + ((size_t)nbS + 2) * 4);
    const bool fast_ok = (NT <= MAXNT) && (off <= ws_size);

    unsigned short* slabA = (unsigned short*)(ws + o_slabA);
    unsigned short* Wb1   = (unsigned short*)(ws + o_Wb1);
    unsigned short* Wb2   = (unsigned short*)(ws + o_Wb2);
    float* stats          = (float*)(ws + o_stats);
    float* h2             = (float*)(ws + o_h2);
    unsigned* pay         = (unsigned*)(ws + o_pay);
    int* cnt              = (int*)(ws + o_cnt);
    int* sptr             = (int*)(ws + o_sptr);
    int* bsum             = (int*)(ws + o_bsum);

    const dim3 b256(256);
    const int gCvt = (int)((total / 4 + 255) / 256);
    const int kelems = K * 16384;

    hipLaunchKernelGGL(zero_f32, dim3(1), b256, 0, stream, stats, (long)1024);
    hipLaunchKernelGGL(cvt_bf16, dim3(gCvt), b256, 0, stream, x, slabA, total);
    hipLaunchKernelGGL(prep_w, dim3((2 * kelems + 255) / 256), b256, 0, stream,
                       W1, W2, Wb1, Wb2, kelems);

    if (fast_ok) {
        const int gSort = K * NCH;
        hipLaunchKernelGGL(pass_hist32, dim3(gSort), b256, 0, stream, idx_out, cnt, n, NT, NCH);
        hipLaunchKernelGGL(scan_part, dim3((int)nbS), b256, 0, stream, cnt, bsum, (int)nbinsS);
        hipLaunchKernelGGL(scan_bsum, dim3(1), dim3(64), 0, stream, bsum, (int)nbS, sptr, (int)nbinsS);
        hipLaunchKernelGGL(scan_final, dim3((int)nbS), b256, 0, stream, cnt, bsum, sptr, (int)nbinsS);
        hipLaunchKernelGGL(pass_scatter32, dim3(gSort), b256, 0, stream,
                           idx_out, idx_in, sptr, pay, n, NT, NCH);

        const int gConv = (NT + 3) / 4;
        const int KH = (K + 1) / 2;
        for (int conv = 0; conv < 2; ++conv) {
            const unsigned short* Wb = conv ? Wb2 : Wb1;
            float* st = stats + conv * 512;
            hipLaunchKernelGGL(conv_ms, dim3(gConv, 2), b256, 0, stream,
                               slabA, Wb, pay, sptr, acc, h2, n, NT, NCH, K, KH);
            hipLaunchKernelGGL(bn_stats_merge, dim3((n + 255) / 256), b256, 0, stream,
                               acc, h2, st, n);
            hipLaunchKernelGGL(bn_finalize, dim3(1), dim3(128), 0, stream, st,
                               conv ? g2 : g1, conv ? b2 : b1, 1.0f / n);
            if (conv == 0)
                hipLaunchKernelGGL(bn_relu_bf16, dim3(gCvt), b256, 0, stream, acc, st, slabA, total);
            else
                hipLaunchKernelGGL(bn_res_relu, dim3(gCvt), b256, 0, stream, acc, st, x, total);
        }
    } else {
        for (int conv = 0; conv < 2; ++conv) {
            const unsigned short* Wb = conv ? Wb2 : Wb1;
            float* st = stats + conv * 512;
            hipLaunchKernelGGL(zero_f32, dim3(gCvt), b256, 0, stream, acc, total);
            hipLaunchKernelGGL(conv_atomic, dim3((n + 255) / 256, K), dim3(512), 0, stream,
                               slabA, Wb, idx_in, idx_out, acc, n);
            hipLaunchKernelGGL(bn_stats, dim3((n + 255) / 256), b256, 0, stream, acc, st, n);
            hipLaunchKernelGGL(bn_finalize, dim3(1), dim3(128), 0, stream, st,
                               conv ? g2 : g1, conv ? b2 : b1, 1.0f / n);
            if (conv == 0)
                hipLaunchKernelGGL(bn_relu_bf16, dim3(gCvt), b256, 0, stream, acc, st, slabA, total);
            else
                hipLaunchKernelGGL(bn_res_relu, dim3(gCvt), b256, 0, stream, acc, st, x, total);
        }
    }
}